// Round 1
// baseline (16721.255 us; speedup 1.0000x reference)
//
#include <hip/hip_runtime.h>
#include <math.h>

#define IN_F 256
#define OUT_F 64

// ---------------------------------------------------------------------------
// zero workspace channel buffers (d_ws is re-poisoned to 0xAA before each call)
__global__ __launch_bounds__(256) void zero_kernel(float4* __restrict__ p, long n4) {
  long t = (long)blockIdx.x * blockDim.x + threadIdx.x;
  long stride = (long)gridDim.x * blockDim.x;
  for (; t < n4; t += stride) p[t] = make_float4(0.f, 0.f, 0.f, 0.f);
}

// ---------------------------------------------------------------------------
// s0 = x @ W   [N,256]x[256,64] fp32. Wave per row; lane = output col.
// Row staged in a float4 per lane, broadcast via shfl.
__global__ __launch_bounds__(256) void gemm_kernel(const float* __restrict__ x,
    const float* __restrict__ W, float* __restrict__ s0, int N) {
  int lane = threadIdx.x & 63;
  int gw = (blockIdx.x * blockDim.x + threadIdx.x) >> 6;
  int nw = (gridDim.x * blockDim.x) >> 6;
  for (int i = gw; i < N; i += nw) {
    const float4 xv = ((const float4*)(x + (size_t)i * IN_F))[lane];
    float acc = 0.f;
#pragma unroll 8
    for (int o = 0; o < 64; ++o) {
      float a0 = __shfl(xv.x, o);
      float a1 = __shfl(xv.y, o);
      float a2 = __shfl(xv.z, o);
      float a3 = __shfl(xv.w, o);
      const float* wp = W + o * 4 * OUT_F + lane;
      acc = fmaf(a0, wp[0],         acc);
      acc = fmaf(a1, wp[OUT_F],     acc);
      acc = fmaf(a2, wp[2 * OUT_F], acc);
      acc = fmaf(a3, wp[3 * OUT_F], acc);
    }
    s0[(size_t)i * OUT_F + lane] = acc;
  }
}

// ---------------------------------------------------------------------------
// COO SpMM: out[r,:] += v * xin[c,:]. 16 threads per edge, float4 per thread.
__global__ __launch_bounds__(256) void spmm_atomic(const int* __restrict__ rows,
    const int* __restrict__ cols, const float* __restrict__ val,
    const float* __restrict__ xin, float* __restrict__ out, int E) {
  int t = blockIdx.x * blockDim.x + threadIdx.x;
  int e = t >> 4;
  if (e >= E) return;
  int g = t & 15;
  int r = rows[e];
  int c = cols[e];
  float v = val[e];
  float4 xv = ((const float4*)(xin + (size_t)c * OUT_F))[g];
  float* o = out + (size_t)r * OUT_F + g * 4;
  atomicAdd(o + 0, v * xv.x);
  atomicAdd(o + 1, v * xv.y);
  atomicAdd(o + 2, v * xv.z);
  atomicAdd(o + 3, v * xv.w);
}

// ---------------------------------------------------------------------------
// Fused: e (raw-reshape dots), softmax, attention store, h_prime mod-6 gather.
// chan = 6 contiguous [N*64] buffers: hA, hA2, hA3, hs1, hs2, hs3 (hs* stored
// un-abs'ed; fabs applied at read, matching h_s = abs(spmm(...))).
__global__ __launch_bounds__(256) void fuse_kernel(const float* __restrict__ s0,
    const float* __restrict__ chan, const float* __restrict__ a,
    float* __restrict__ out_h, float* __restrict__ out_att, int N) {
  int lane = threadIdx.x & 63;
  int i = (blockIdx.x * blockDim.x + threadIdx.x) >> 6;
  if (i >= N) return;
  size_t NF = (size_t)N * OUT_F;
  float e[6];
  int half = N >> 1;
  if (i < half) {
    // rows 2i, 2i+1 of s0
    float lo = s0[(size_t)(2 * i) * OUT_F + lane];
    float hi = s0[(size_t)(2 * i + 1) * OUT_F + lane];
#pragma unroll
    for (int ch = 0; ch < 6; ++ch) {
      float p = fmaf(lo, a[ch * 128 + lane], hi * a[ch * 128 + 64 + lane]);
#pragma unroll
      for (int off = 32; off; off >>= 1) p += __shfl_xor(p, off);
      e[ch] = p;
    }
  } else {
    // rows 2i-N, 2i-N+1 of each channel
    int r = 2 * i - N;
#pragma unroll
    for (int ch = 0; ch < 6; ++ch) {
      float lo = chan[(size_t)ch * NF + (size_t)r * OUT_F + lane];
      float hi = chan[(size_t)ch * NF + (size_t)(r + 1) * OUT_F + lane];
      if (ch >= 3) { lo = fabsf(lo); hi = fabsf(hi); }
      float p = fmaf(lo, a[ch * 128 + lane], hi * a[ch * 128 + 64 + lane]);
#pragma unroll
      for (int off = 32; off; off >>= 1) p += __shfl_xor(p, off);
      e[ch] = p;
    }
  }
  // softmax over the 6 channels (every lane has the full e vector)
  float m = e[0];
#pragma unroll
  for (int ch = 1; ch < 6; ++ch) m = fmaxf(m, e[ch]);
  float s = 0.f;
#pragma unroll
  for (int ch = 0; ch < 6; ++ch) { e[ch] = expf(e[ch] - m); s += e[ch]; }
  float inv = 1.f / s;
#pragma unroll
  for (int ch = 0; ch < 6; ++ch) e[ch] *= inv;

  if (lane < 6) {
    float v = e[0];
    if (lane == 1) v = e[1];
    if (lane == 2) v = e[2];
    if (lane == 3) v = e[3];
    if (lane == 4) v = e[4];
    if (lane == 5) v = e[5];
    out_att[(size_t)i * 6 + lane] = v;
  }

  // h_prime[i][q] = (1/6) * sum_p att[p] * chans[(p*64+q)%6][i][(p*64+q)/6]
  float hp = 0.f;
#pragma unroll
  for (int p = 0; p < 6; ++p) {
    int idx = p * 64 + lane;
    int c = idx % 6;
    int j = idx / 6;
    float v = chan[(size_t)c * NF + (size_t)i * OUT_F + j];
    v = (c >= 3) ? fabsf(v) : v;
    hp = fmaf(e[p], v, hp);
  }
  out_h[(size_t)i * OUT_F + lane] = hp * (1.f / 6.f);
}

// ---------------------------------------------------------------------------
extern "C" void kernel_launch(void* const* d_in, const int* in_sizes, int n_in,
                              void* d_out, int out_size, void* d_ws, size_t ws_size,
                              hipStream_t stream) {
  const float* x      = (const float*)d_in[0];
  const float* W      = (const float*)d_in[1];
  const float* a      = (const float*)d_in[2];
  const int*   A_idx  = (const int*)d_in[3];
  const float* A_val  = (const float*)d_in[4];
  const int*   P1_idx = (const int*)d_in[5];
  const float* P1_val = (const float*)d_in[6];
  const int*   P2_idx = (const int*)d_in[7];
  const float* P2_val = (const float*)d_in[8];
  const int*   P3_idx = (const int*)d_in[9];
  const float* P3_val = (const float*)d_in[10];

  int N = in_sizes[0] / IN_F;  // 100000
  int E = in_sizes[4];         // 3200000

  size_t NF = (size_t)N * OUT_F;
  float* s0   = (float*)d_ws;          // [N,64]
  float* chan = s0 + NF;               // 6 contiguous [N,64] channel buffers
  float* hA  = chan + 0 * NF;
  float* hA2 = chan + 1 * NF;
  float* hA3 = chan + 2 * NF;
  float* hs1 = chan + 3 * NF;
  float* hs2 = chan + 4 * NF;
  float* hs3 = chan + 5 * NF;

  float* out_h   = (float*)d_out;      // [N,64]
  float* out_att = out_h + NF;         // [N,6]

  long n4 = (long)(6 * NF / 4);
  zero_kernel<<<2048, 256, 0, stream>>>((float4*)chan, n4);
  gemm_kernel<<<2048, 256, 0, stream>>>(x, W, s0, N);

  int sblocks = (int)(((long)E * 16 + 255) / 256);
  spmm_atomic<<<sblocks, 256, 0, stream>>>(A_idx,  A_idx  + E, A_val,  s0,  hA,  E);
  spmm_atomic<<<sblocks, 256, 0, stream>>>(A_idx,  A_idx  + E, A_val,  hA,  hA2, E);
  spmm_atomic<<<sblocks, 256, 0, stream>>>(A_idx,  A_idx  + E, A_val,  hA2, hA3, E);
  spmm_atomic<<<sblocks, 256, 0, stream>>>(P1_idx, P1_idx + E, P1_val, s0,  hs1, E);
  spmm_atomic<<<sblocks, 256, 0, stream>>>(P2_idx, P2_idx + E, P2_val, s0,  hs2, E);
  spmm_atomic<<<sblocks, 256, 0, stream>>>(P3_idx, P3_idx + E, P3_val, s0,  hs3, E);

  int fblocks = (N * 64 + 255) / 256;
  fuse_kernel<<<fblocks, 256, 0, stream>>>(s0, chan, a, out_h, out_att, N);
}

// Round 2
// 2870.566 us; speedup vs baseline: 5.8251x; 5.8251x over previous
//
#include <hip/hip_runtime.h>
#include <math.h>

#define IN_F 256
#define OUT_F 64

// ---------------------------------------------------------------------------
__global__ __launch_bounds__(256) void zero_f4_kernel(float4* __restrict__ p, long n4) {
  long t = (long)blockIdx.x * blockDim.x + threadIdx.x;
  long stride = (long)gridDim.x * blockDim.x;
  for (; t < n4; t += stride) p[t] = make_float4(0.f, 0.f, 0.f, 0.f);
}

__global__ __launch_bounds__(256) void zero_i_kernel(int* __restrict__ p, int n) {
  int t = blockIdx.x * blockDim.x + threadIdx.x;
  int stride = gridDim.x * blockDim.x;
  for (; t < n; t += stride) p[t] = 0;
}

// ---------------------------------------------------------------------------
// s0 = x @ W   [N,256]x[256,64] fp32. Wave per row; lane = output col.
__global__ __launch_bounds__(256) void gemm_kernel(const float* __restrict__ x,
    const float* __restrict__ W, float* __restrict__ s0, int N) {
  int lane = threadIdx.x & 63;
  int gw = (blockIdx.x * blockDim.x + threadIdx.x) >> 6;
  int nw = (gridDim.x * blockDim.x) >> 6;
  for (int i = gw; i < N; i += nw) {
    const float4 xv = ((const float4*)(x + (size_t)i * IN_F))[lane];
    float acc = 0.f;
#pragma unroll 8
    for (int o = 0; o < 64; ++o) {
      float a0 = __shfl(xv.x, o);
      float a1 = __shfl(xv.y, o);
      float a2 = __shfl(xv.z, o);
      float a3 = __shfl(xv.w, o);
      const float* wp = W + o * 4 * OUT_F + lane;
      acc = fmaf(a0, wp[0],         acc);
      acc = fmaf(a1, wp[OUT_F],     acc);
      acc = fmaf(a2, wp[2 * OUT_F], acc);
      acc = fmaf(a3, wp[3 * OUT_F], acc);
    }
    s0[(size_t)i * OUT_F + lane] = acc;
  }
}

// ---------------------------------------------------------------------------
// Counting-sort pipeline: hist -> hierarchical exclusive scan -> scatter.
__global__ __launch_bounds__(256) void hist_kernel(const int* __restrict__ rows,
    int* __restrict__ cnt, int E) {
  int t = blockIdx.x * blockDim.x + threadIdx.x;
  int stride = gridDim.x * blockDim.x;
  for (; t < E; t += stride) atomicAdd(&cnt[rows[t]], 1);
}

__global__ __launch_bounds__(256) void block_sum_kernel(const int* __restrict__ cnt,
    int* __restrict__ bsum, int n) {
  __shared__ int sb[256];
  int i = blockIdx.x * 256 + threadIdx.x;
  sb[threadIdx.x] = (i < n) ? cnt[i] : 0;
  __syncthreads();
  for (int s = 128; s > 0; s >>= 1) {
    if (threadIdx.x < s) sb[threadIdx.x] += sb[threadIdx.x + s];
    __syncthreads();
  }
  if (threadIdx.x == 0) bsum[blockIdx.x] = sb[0];
}

__global__ __launch_bounds__(512) void scan_bsum_kernel(int* __restrict__ bsum, int nb) {
  __shared__ int sb[512];
  int t = threadIdx.x;
  int v = (t < nb) ? bsum[t] : 0;
  sb[t] = v;
  __syncthreads();
  for (int s = 1; s < 512; s <<= 1) {
    int u = (t >= s) ? sb[t - s] : 0;
    __syncthreads();
    sb[t] += u;
    __syncthreads();
  }
  if (t < nb) bsum[t] = sb[t] - v;  // exclusive
}

__global__ __launch_bounds__(256) void scan_final_kernel(const int* __restrict__ cnt,
    const int* __restrict__ bsum, int* __restrict__ off, int n) {
  __shared__ int sb[256];
  int i = blockIdx.x * 256 + threadIdx.x;
  int v = (i < n) ? cnt[i] : 0;
  sb[threadIdx.x] = v;
  __syncthreads();
  for (int s = 1; s < 256; s <<= 1) {
    int u = (threadIdx.x >= s) ? sb[threadIdx.x - s] : 0;
    __syncthreads();
    sb[threadIdx.x] += u;
    __syncthreads();
  }
  if (i < n) off[i] = bsum[blockIdx.x] + sb[threadIdx.x] - v;  // exclusive
}

// Scatter edges into row-sorted order. Mutates off: afterwards off[r] = end
// of segment r (segment start = off[r-1], or 0 for r==0).
__global__ __launch_bounds__(256) void scatter_kernel(const int* __restrict__ rows,
    const int* __restrict__ cols, const float* __restrict__ val,
    int* __restrict__ off, uint2* __restrict__ S, int E) {
  int t = blockIdx.x * blockDim.x + threadIdx.x;
  int stride = gridDim.x * blockDim.x;
  for (; t < E; t += stride) {
    int r = rows[t];
    int pos = atomicAdd(&off[r], 1);
    S[pos] = make_uint2((unsigned)cols[t], __float_as_uint(val[t]));
  }
}

// Gather SpMM: wave per row, lane = feature. offEnd[r] = segment end.
__global__ __launch_bounds__(256) void spmm_gather(const uint2* __restrict__ S,
    const int* __restrict__ offEnd, const float* __restrict__ xin,
    float* __restrict__ out, int N) {
  int lane = threadIdx.x & 63;
  int r = (blockIdx.x * blockDim.x + threadIdx.x) >> 6;
  if (r >= N) return;
  int s = (r == 0) ? 0 : offEnd[r - 1];
  int e = offEnd[r];
  float acc = 0.f;
  for (int k = s; k < e; k += 64) {
    int rem = e - k;
    uint2 ed = make_uint2(0u, 0u);
    if (lane < rem) ed = S[k + lane];
    int m = rem < 64 ? rem : 64;
    for (int j = 0; j < m; ++j) {
      int c = __shfl((int)ed.x, j);
      float v = __shfl(__uint_as_float(ed.y), j);
      acc = fmaf(v, xin[(size_t)c * OUT_F + lane], acc);
    }
  }
  out[(size_t)r * OUT_F + lane] = acc;
}

// ---------------------------------------------------------------------------
// Round-1 fallback: COO SpMM via atomics (used only if ws too small for sort).
__global__ __launch_bounds__(256) void spmm_atomic(const int* __restrict__ rows,
    const int* __restrict__ cols, const float* __restrict__ val,
    const float* __restrict__ xin, float* __restrict__ out, int E) {
  int t = blockIdx.x * blockDim.x + threadIdx.x;
  int e = t >> 4;
  if (e >= E) return;
  int g = t & 15;
  int r = rows[e];
  int c = cols[e];
  float v = val[e];
  float4 xv = ((const float4*)(xin + (size_t)c * OUT_F))[g];
  float* o = out + (size_t)r * OUT_F + g * 4;
  atomicAdd(o + 0, v * xv.x);
  atomicAdd(o + 1, v * xv.y);
  atomicAdd(o + 2, v * xv.z);
  atomicAdd(o + 3, v * xv.w);
}

// ---------------------------------------------------------------------------
// Fused epilogue: e (raw-reshape dots), softmax, attention store, h_prime.
__global__ __launch_bounds__(256) void fuse_kernel(const float* __restrict__ s0,
    const float* __restrict__ chan, const float* __restrict__ a,
    float* __restrict__ out_h, float* __restrict__ out_att, int N) {
  int lane = threadIdx.x & 63;
  int i = (blockIdx.x * blockDim.x + threadIdx.x) >> 6;
  if (i >= N) return;
  size_t NF = (size_t)N * OUT_F;
  float e[6];
  int half = N >> 1;
  if (i < half) {
    float lo = s0[(size_t)(2 * i) * OUT_F + lane];
    float hi = s0[(size_t)(2 * i + 1) * OUT_F + lane];
#pragma unroll
    for (int ch = 0; ch < 6; ++ch) {
      float p = fmaf(lo, a[ch * 128 + lane], hi * a[ch * 128 + 64 + lane]);
#pragma unroll
      for (int off = 32; off; off >>= 1) p += __shfl_xor(p, off);
      e[ch] = p;
    }
  } else {
    int r = 2 * i - N;
#pragma unroll
    for (int ch = 0; ch < 6; ++ch) {
      float lo = chan[(size_t)ch * NF + (size_t)r * OUT_F + lane];
      float hi = chan[(size_t)ch * NF + (size_t)(r + 1) * OUT_F + lane];
      if (ch >= 3) { lo = fabsf(lo); hi = fabsf(hi); }
      float p = fmaf(lo, a[ch * 128 + lane], hi * a[ch * 128 + 64 + lane]);
#pragma unroll
      for (int off = 32; off; off >>= 1) p += __shfl_xor(p, off);
      e[ch] = p;
    }
  }
  float m = e[0];
#pragma unroll
  for (int ch = 1; ch < 6; ++ch) m = fmaxf(m, e[ch]);
  float s = 0.f;
#pragma unroll
  for (int ch = 0; ch < 6; ++ch) { e[ch] = expf(e[ch] - m); s += e[ch]; }
  float inv = 1.f / s;
#pragma unroll
  for (int ch = 0; ch < 6; ++ch) e[ch] *= inv;

  if (lane < 6) {
    float v = e[0];
    if (lane == 1) v = e[1];
    if (lane == 2) v = e[2];
    if (lane == 3) v = e[3];
    if (lane == 4) v = e[4];
    if (lane == 5) v = e[5];
    out_att[(size_t)i * 6 + lane] = v;
  }

  float hp = 0.f;
#pragma unroll
  for (int p = 0; p < 6; ++p) {
    int idx = p * 64 + lane;
    int c = idx % 6;
    int j = idx / 6;
    float v = chan[(size_t)c * NF + (size_t)i * OUT_F + j];
    v = (c >= 3) ? fabsf(v) : v;
    hp = fmaf(e[p], v, hp);
  }
  out_h[(size_t)i * OUT_F + lane] = hp * (1.f / 6.f);
}

// ---------------------------------------------------------------------------
extern "C" void kernel_launch(void* const* d_in, const int* in_sizes, int n_in,
                              void* d_out, int out_size, void* d_ws, size_t ws_size,
                              hipStream_t stream) {
  const float* x      = (const float*)d_in[0];
  const float* W      = (const float*)d_in[1];
  const float* a      = (const float*)d_in[2];
  const int*   A_idx  = (const int*)d_in[3];
  const float* A_val  = (const float*)d_in[4];
  const int*   P1_idx = (const int*)d_in[5];
  const float* P1_val = (const float*)d_in[6];
  const int*   P2_idx = (const int*)d_in[7];
  const float* P2_val = (const float*)d_in[8];
  const int*   P3_idx = (const int*)d_in[9];
  const float* P3_val = (const float*)d_in[10];

  int N = in_sizes[0] / IN_F;  // 100000
  int E = in_sizes[4];         // 3200000

  size_t NF = (size_t)N * OUT_F;
  float* s0   = (float*)d_ws;          // [N,64]
  float* chan = s0 + NF;               // 6 contiguous [N,64] channel buffers
  float* hA  = chan + 0 * NF;
  float* hA2 = chan + 1 * NF;
  float* hA3 = chan + 2 * NF;
  float* hs1 = chan + 3 * NF;
  float* hs2 = chan + 4 * NF;
  float* hs3 = chan + 5 * NF;

  float* out_h   = (float*)d_out;      // [N,64]
  float* out_att = out_h + NF;         // [N,6]

  int nchunks = (N + 255) / 256;       // 391 <= 512
  size_t need = 7 * NF * 4 + (size_t)E * 8 + (size_t)(2 * N + 512) * 4;

  int fblocks = (N * 64 + 255) / 256;

  if (ws_size >= need) {
    uint2* S   = (uint2*)(chan + 6 * NF);      // [E] sorted (col,val)
    int* cnt   = (int*)(S + E);                // [N]
    int* off   = cnt + N;                      // [N] -> becomes segment-end
    int* bsum  = off + N;                      // [512]

    gemm_kernel<<<2048, 256, 0, stream>>>(x, W, s0, N);

    int hblocks = (E + 255) / 256;
    int gblocks = (N * 64 + 255) / 256;

    // helper macro: sort one operator into S/off
#define SORT_OP(IDX, VAL)                                                        \
    do {                                                                         \
      zero_i_kernel<<<512, 256, 0, stream>>>(cnt, N);                            \
      hist_kernel<<<hblocks, 256, 0, stream>>>(IDX, cnt, E);                     \
      block_sum_kernel<<<nchunks, 256, 0, stream>>>(cnt, bsum, N);               \
      scan_bsum_kernel<<<1, 512, 0, stream>>>(bsum, nchunks);                    \
      scan_final_kernel<<<nchunks, 256, 0, stream>>>(cnt, bsum, off, N);         \
      scatter_kernel<<<hblocks, 256, 0, stream>>>(IDX, IDX + E, VAL, off, S, E); \
    } while (0)

    SORT_OP(A_idx, A_val);
    spmm_gather<<<gblocks, 256, 0, stream>>>(S, off, s0,  hA,  N);
    spmm_gather<<<gblocks, 256, 0, stream>>>(S, off, hA,  hA2, N);
    spmm_gather<<<gblocks, 256, 0, stream>>>(S, off, hA2, hA3, N);
    SORT_OP(P1_idx, P1_val);
    spmm_gather<<<gblocks, 256, 0, stream>>>(S, off, s0, hs1, N);
    SORT_OP(P2_idx, P2_val);
    spmm_gather<<<gblocks, 256, 0, stream>>>(S, off, s0, hs2, N);
    SORT_OP(P3_idx, P3_val);
    spmm_gather<<<gblocks, 256, 0, stream>>>(S, off, s0, hs3, N);
#undef SORT_OP
  } else {
    // Fallback: round-1 atomic path.
    long n4 = (long)(6 * NF / 4);
    zero_f4_kernel<<<2048, 256, 0, stream>>>((float4*)chan, n4);
    gemm_kernel<<<2048, 256, 0, stream>>>(x, W, s0, N);
    int sblocks = (int)(((long)E * 16 + 255) / 256);
    spmm_atomic<<<sblocks, 256, 0, stream>>>(A_idx,  A_idx  + E, A_val,  s0,  hA,  E);
    spmm_atomic<<<sblocks, 256, 0, stream>>>(A_idx,  A_idx  + E, A_val,  hA,  hA2, E);
    spmm_atomic<<<sblocks, 256, 0, stream>>>(A_idx,  A_idx  + E, A_val,  hA2, hA3, E);
    spmm_atomic<<<sblocks, 256, 0, stream>>>(P1_idx, P1_idx + E, P1_val, s0,  hs1, E);
    spmm_atomic<<<sblocks, 256, 0, stream>>>(P2_idx, P2_idx + E, P2_val, s0,  hs2, E);
    spmm_atomic<<<sblocks, 256, 0, stream>>>(P3_idx, P3_idx + E, P3_val, s0,  hs3, E);
  }

  fuse_kernel<<<fblocks, 256, 0, stream>>>(s0, chan, a, out_h, out_att, N);
}

// Round 3
// 2821.477 us; speedup vs baseline: 5.9264x; 1.0174x over previous
//
#include <hip/hip_runtime.h>
#include <math.h>

#define IN_F 256
#define OUT_F 64

// ---------------------------------------------------------------------------
__global__ __launch_bounds__(256) void zero_i_kernel(int* __restrict__ p, int n) {
  int t = blockIdx.x * blockDim.x + threadIdx.x;
  int stride = gridDim.x * blockDim.x;
  for (; t < n; t += stride) p[t] = 0;
}

// ---------------------------------------------------------------------------
// s0 = x @ W  [N,256]x[256,64] fp32.
// W transposed into LDS (XOR-swizzled float4 rows, 64 KB). Wave per row;
// lane = out col. x row read at wave-uniform addresses (readfirstlane) ->
// broadcast loads, no per-lane traffic, no shfl.
__global__ __launch_bounds__(256) void gemm_kernel(const float* __restrict__ x,
    const float* __restrict__ W, float* __restrict__ s0, int N) {
  __shared__ float4 Wt4[64 * 64];  // Wt4[n*64 + (k4 ^ n)] = W[4k..4k+3][n], 64 KB
  float* Wtf = (float*)Wt4;
  for (int idx = threadIdx.x; idx < 64 * 256; idx += 256) {
    int k = idx >> 6, n = idx & 63;          // W[k][n], coalesced global read
    Wtf[(n * 64 + ((k >> 2) ^ n)) * 4 + (k & 3)] = W[idx];
  }
  __syncthreads();
  int lane = threadIdx.x & 63;
  int gw = (blockIdx.x * 256 + threadIdx.x) >> 6;
  int nw = (gridDim.x * 256) >> 6;
  const float4* wrow = &Wt4[lane * 64];
  for (int r = gw; r < N; r += nw) {
    int ru = __builtin_amdgcn_readfirstlane(r);
    const float4* xr = (const float4*)(x + (size_t)ru * IN_F);
    float acc = 0.f;
#pragma unroll 8
    for (int k4 = 0; k4 < 64; ++k4) {
      float4 xv = xr[k4];                    // wave-uniform broadcast load
      float4 wv = wrow[k4 ^ lane];           // ds_read_b128, swizzled banks
      acc = fmaf(xv.x, wv.x, acc);
      acc = fmaf(xv.y, wv.y, acc);
      acc = fmaf(xv.z, wv.z, acc);
      acc = fmaf(xv.w, wv.w, acc);
    }
    s0[(size_t)ru * OUT_F + lane] = acc;
  }
}

// ---------------------------------------------------------------------------
// Counting sort, batched over gridDim.y operators (op = blockIdx.y + op_off).
__global__ __launch_bounds__(256) void hist_kernel(const int* __restrict__ r0,
    const int* __restrict__ r1, const int* __restrict__ r2,
    int* __restrict__ cnt, int E, int N, int op_off) {
  int g = blockIdx.y + op_off;
  const int* rows = (g == 0) ? r0 : (g == 1) ? r1 : r2;
  int* c = cnt + (size_t)blockIdx.y * N;
  int t = blockIdx.x * 256 + threadIdx.x;
  int stride = gridDim.x * 256;
  for (; t < E; t += stride) atomicAdd(&c[rows[t]], 1);
}

__global__ __launch_bounds__(256) void block_sum_kernel(const int* __restrict__ cnt,
    int* __restrict__ bsum, int n) {
  cnt += (size_t)blockIdx.y * n;
  bsum += (size_t)blockIdx.y * 512;
  __shared__ int sb[256];
  int i = blockIdx.x * 256 + threadIdx.x;
  sb[threadIdx.x] = (i < n) ? cnt[i] : 0;
  __syncthreads();
  for (int s = 128; s > 0; s >>= 1) {
    if (threadIdx.x < s) sb[threadIdx.x] += sb[threadIdx.x + s];
    __syncthreads();
  }
  if (threadIdx.x == 0) bsum[blockIdx.x] = sb[0];
}

__global__ __launch_bounds__(512) void scan_bsum_kernel(int* __restrict__ bsum, int nb) {
  bsum += (size_t)blockIdx.x * 512;  // blockIdx.x = operator
  __shared__ int sb[512];
  int t = threadIdx.x;
  int v = (t < nb) ? bsum[t] : 0;
  sb[t] = v;
  __syncthreads();
  for (int s = 1; s < 512; s <<= 1) {
    int u = (t >= s) ? sb[t - s] : 0;
    __syncthreads();
    sb[t] += u;
    __syncthreads();
  }
  if (t < nb) bsum[t] = sb[t] - v;  // exclusive
}

__global__ __launch_bounds__(256) void scan_final_kernel(const int* __restrict__ cnt,
    const int* __restrict__ bsum, int* __restrict__ off, int n) {
  cnt  += (size_t)blockIdx.y * n;
  off  += (size_t)blockIdx.y * n;
  bsum += (size_t)blockIdx.y * 512;
  __shared__ int sb[256];
  int i = blockIdx.x * 256 + threadIdx.x;
  int v = (i < n) ? cnt[i] : 0;
  sb[threadIdx.x] = v;
  __syncthreads();
  for (int s = 1; s < 256; s <<= 1) {
    int u = (threadIdx.x >= s) ? sb[threadIdx.x - s] : 0;
    __syncthreads();
    sb[threadIdx.x] += u;
    __syncthreads();
  }
  if (i < n) off[i] = bsum[blockIdx.x] + sb[threadIdx.x] - v;  // exclusive
}

// Scatter edges into row-sorted order. Afterwards off[r] = segment end.
__global__ __launch_bounds__(256) void scatter_kernel(const int* __restrict__ r0,
    const int* __restrict__ r1, const int* __restrict__ r2,
    const float* __restrict__ v0, const float* __restrict__ v1,
    const float* __restrict__ v2, int* __restrict__ off, uint2* __restrict__ S,
    int E, int N, int op_off) {
  int g = blockIdx.y + op_off;
  const int* rows = (g == 0) ? r0 : (g == 1) ? r1 : r2;
  const float* val = (g == 0) ? v0 : (g == 1) ? v1 : v2;
  const int* cols = rows + E;
  int* o = off + (size_t)blockIdx.y * N;
  uint2* So = S + (size_t)blockIdx.y * E;
  int t = blockIdx.x * 256 + threadIdx.x;
  int stride = gridDim.x * 256;
  for (; t < E; t += stride) {
    int r = rows[t];
    int pos = atomicAdd(&o[r], 1);
    So[pos] = make_uint2((unsigned)cols[t], __float_as_uint(val[t]));
  }
}

// Gather SpMM: wave per row, lane = feature. Edge records read at
// wave-uniform addresses (broadcast), unrolled x4 for MLP of the gathers.
__global__ __launch_bounds__(256) void spmm_gather(const uint2* __restrict__ S,
    const int* __restrict__ offEnd, const float* __restrict__ xin,
    float* __restrict__ out, int N, int Estride) {
  S      += (size_t)blockIdx.y * Estride;
  offEnd += (size_t)blockIdx.y * N;
  out    += (size_t)blockIdx.y * (size_t)N * OUT_F;
  int lane = threadIdx.x & 63;
  int r = (blockIdx.x * 256 + threadIdx.x) >> 6;
  if (r >= N) return;
  r = __builtin_amdgcn_readfirstlane(r);
  int s = (r == 0) ? 0 : offEnd[r - 1];
  int e = offEnd[r];
  float acc = 0.f;
  int j = s;
  for (; j + 4 <= e; j += 4) {
    uint2 e0 = S[j], e1 = S[j + 1], e2 = S[j + 2], e3 = S[j + 3];
    float g0 = xin[(size_t)e0.x * OUT_F + lane];
    float g1 = xin[(size_t)e1.x * OUT_F + lane];
    float g2 = xin[(size_t)e2.x * OUT_F + lane];
    float g3 = xin[(size_t)e3.x * OUT_F + lane];
    acc = fmaf(__uint_as_float(e0.y), g0, acc);
    acc = fmaf(__uint_as_float(e1.y), g1, acc);
    acc = fmaf(__uint_as_float(e2.y), g2, acc);
    acc = fmaf(__uint_as_float(e3.y), g3, acc);
  }
  for (; j < e; ++j) {
    uint2 ed = S[j];
    acc = fmaf(__uint_as_float(ed.y), xin[(size_t)ed.x * OUT_F + lane], acc);
  }
  out[(size_t)r * OUT_F + lane] = acc;
}

// ---------------------------------------------------------------------------
// Fused epilogue: e (raw-reshape dots), softmax, attention store, h_prime.
__global__ __launch_bounds__(256) void fuse_kernel(const float* __restrict__ s0,
    const float* __restrict__ chan, const float* __restrict__ a,
    float* __restrict__ out_h, float* __restrict__ out_att, int N) {
  int lane = threadIdx.x & 63;
  int i = (blockIdx.x * blockDim.x + threadIdx.x) >> 6;
  if (i >= N) return;
  size_t NF = (size_t)N * OUT_F;
  float e[6];
  int half = N >> 1;
  if (i < half) {
    float lo = s0[(size_t)(2 * i) * OUT_F + lane];
    float hi = s0[(size_t)(2 * i + 1) * OUT_F + lane];
#pragma unroll
    for (int ch = 0; ch < 6; ++ch) {
      float p = fmaf(lo, a[ch * 128 + lane], hi * a[ch * 128 + 64 + lane]);
#pragma unroll
      for (int off = 32; off; off >>= 1) p += __shfl_xor(p, off);
      e[ch] = p;
    }
  } else {
    int r = 2 * i - N;
#pragma unroll
    for (int ch = 0; ch < 6; ++ch) {
      float lo = chan[(size_t)ch * NF + (size_t)r * OUT_F + lane];
      float hi = chan[(size_t)ch * NF + (size_t)(r + 1) * OUT_F + lane];
      if (ch >= 3) { lo = fabsf(lo); hi = fabsf(hi); }
      float p = fmaf(lo, a[ch * 128 + lane], hi * a[ch * 128 + 64 + lane]);
#pragma unroll
      for (int off = 32; off; off >>= 1) p += __shfl_xor(p, off);
      e[ch] = p;
    }
  }
  float m = e[0];
#pragma unroll
  for (int ch = 1; ch < 6; ++ch) m = fmaxf(m, e[ch]);
  float s = 0.f;
#pragma unroll
  for (int ch = 0; ch < 6; ++ch) { e[ch] = expf(e[ch] - m); s += e[ch]; }
  float inv = 1.f / s;
#pragma unroll
  for (int ch = 0; ch < 6; ++ch) e[ch] *= inv;

  if (lane < 6) {
    float v = e[0];
    if (lane == 1) v = e[1];
    if (lane == 2) v = e[2];
    if (lane == 3) v = e[3];
    if (lane == 4) v = e[4];
    if (lane == 5) v = e[5];
    out_att[(size_t)i * 6 + lane] = v;
  }

  float hp = 0.f;
#pragma unroll
  for (int p = 0; p < 6; ++p) {
    int idx = p * 64 + lane;
    int c = idx % 6;
    int j = idx / 6;
    float v = chan[(size_t)c * NF + (size_t)i * OUT_F + j];
    v = (c >= 3) ? fabsf(v) : v;
    hp = fmaf(e[p], v, hp);
  }
  out_h[(size_t)i * OUT_F + lane] = hp * (1.f / 6.f);
}

// ---------------------------------------------------------------------------
extern "C" void kernel_launch(void* const* d_in, const int* in_sizes, int n_in,
                              void* d_out, int out_size, void* d_ws, size_t ws_size,
                              hipStream_t stream) {
  const float* x      = (const float*)d_in[0];
  const float* W      = (const float*)d_in[1];
  const float* a      = (const float*)d_in[2];
  const int*   A_idx  = (const int*)d_in[3];
  const float* A_val  = (const float*)d_in[4];
  const int*   P1_idx = (const int*)d_in[5];
  const float* P1_val = (const float*)d_in[6];
  const int*   P2_idx = (const int*)d_in[7];
  const float* P2_val = (const float*)d_in[8];
  const int*   P3_idx = (const int*)d_in[9];
  const float* P3_val = (const float*)d_in[10];

  int N = in_sizes[0] / IN_F;  // 100000
  int E = in_sizes[4];         // 3200000

  size_t NF = (size_t)N * OUT_F;
  float* s0   = (float*)d_ws;
  float* chan = s0 + NF;               // 6 contiguous [N,64] channel buffers
  float* hA  = chan + 0 * NF;
  float* hA2 = chan + 1 * NF;
  float* hA3 = chan + 2 * NF;
  float* hs1 = chan + 3 * NF;

  float* out_h   = (float*)d_out;
  float* out_att = out_h + NF;

  int nchunks = (N + 255) / 256;       // 391 <= 512
  int hblocks = (E + 255) / 256;
  int gblocks = (N * 64 + 255) / 256;
  int fblocks = (N * 64 + 255) / 256;

  // Batched layout: S_A[E] + S_P[3E] + cntA[N]+offA[N] + cntP[3N]+offP[3N] + bsums
  uint2* S_A  = (uint2*)(chan + 6 * NF);
  uint2* S_P  = S_A + E;
  int* cntA   = (int*)(S_P + (size_t)3 * E);
  int* offA   = cntA + N;
  int* cntP   = offA + N;
  int* offP   = cntP + 3 * N;
  int* bsumA  = offP + 3 * N;
  int* bsumP  = bsumA + 512;
  size_t need_batched = (size_t)((char*)(bsumP + 3 * 512) - (char*)d_ws);

  gemm_kernel<<<512, 256, 0, stream>>>(x, W, s0, N);

  // ---- A operator: sort once, gather 3x (chain) ----
  zero_i_kernel<<<512, 256, 0, stream>>>(cntA, N);
  hist_kernel<<<dim3(hblocks, 1), 256, 0, stream>>>(A_idx, A_idx, A_idx, cntA, E, N, 0);
  block_sum_kernel<<<dim3(nchunks, 1), 256, 0, stream>>>(cntA, bsumA, N);
  scan_bsum_kernel<<<1, 512, 0, stream>>>(bsumA, nchunks);
  scan_final_kernel<<<dim3(nchunks, 1), 256, 0, stream>>>(cntA, bsumA, offA, N);
  scatter_kernel<<<dim3(hblocks, 1), 256, 0, stream>>>(A_idx, A_idx, A_idx,
      A_val, A_val, A_val, offA, S_A, E, N, 0);
  spmm_gather<<<dim3(gblocks, 1), 256, 0, stream>>>(S_A, offA, s0,  hA,  N, 0);
  spmm_gather<<<dim3(gblocks, 1), 256, 0, stream>>>(S_A, offA, hA,  hA2, N, 0);
  spmm_gather<<<dim3(gblocks, 1), 256, 0, stream>>>(S_A, offA, hA2, hA3, N, 0);

  if (ws_size >= need_batched) {
    // ---- P1..P3 batched through one pipeline (gridDim.y = 3) ----
    zero_i_kernel<<<1024, 256, 0, stream>>>(cntP, 3 * N);
    hist_kernel<<<dim3(hblocks, 3), 256, 0, stream>>>(P1_idx, P2_idx, P3_idx, cntP, E, N, 0);
    block_sum_kernel<<<dim3(nchunks, 3), 256, 0, stream>>>(cntP, bsumP, N);
    scan_bsum_kernel<<<3, 512, 0, stream>>>(bsumP, nchunks);
    scan_final_kernel<<<dim3(nchunks, 3), 256, 0, stream>>>(cntP, bsumP, offP, N);
    scatter_kernel<<<dim3(hblocks, 3), 256, 0, stream>>>(P1_idx, P2_idx, P3_idx,
        P1_val, P2_val, P3_val, offP, S_P, E, N, 0);
    spmm_gather<<<dim3(gblocks, 3), 256, 0, stream>>>(S_P, offP, s0, hs1, N, E);
  } else {
    // ---- sequential fallback: reuse A scratch per P op ----
    for (int o = 0; o < 3; ++o) {
      zero_i_kernel<<<512, 256, 0, stream>>>(cntA, N);
      hist_kernel<<<dim3(hblocks, 1), 256, 0, stream>>>(P1_idx, P2_idx, P3_idx, cntA, E, N, o);
      block_sum_kernel<<<dim3(nchunks, 1), 256, 0, stream>>>(cntA, bsumA, N);
      scan_bsum_kernel<<<1, 512, 0, stream>>>(bsumA, nchunks);
      scan_final_kernel<<<dim3(nchunks, 1), 256, 0, stream>>>(cntA, bsumA, offA, N);
      scatter_kernel<<<dim3(hblocks, 1), 256, 0, stream>>>(P1_idx, P2_idx, P3_idx,
          P1_val, P2_val, P3_val, offA, S_A, E, N, o);
      spmm_gather<<<dim3(gblocks, 1), 256, 0, stream>>>(S_A, offA, s0, hs1 + (size_t)o * NF, N, 0);
    }
  }

  fuse_kernel<<<fblocks, 256, 0, stream>>>(s0, chan, a, out_h, out_att, N);
}